// Round 8
// baseline (312.710 us; speedup 1.0000x reference)
//
#include <hip/hip_runtime.h>
#include <hip/hip_bf16.h>

// Self-attention: B=4, S=4096, D=512, f32 in/out, bf16 MFMA internally.
// cvt(q,k,v)->bf16 (z=3); W transpose->bf16 (z=4); proj GEMM (NT, z=3);
// VWT[b] = (v_proj @ Wo)^T via NT GEMM; E: P' = exp(qp@kp^T * scale) -> P
// region (z=4), per-(block,wave) partial row sums -> PART (deterministic,
// NO atomics); reduce_partials: ROWSUM = sum(PART); out = (P'@VWT^T)/rowsum
// + bo -> d_out (f32, z=4).  Softmax = exp/rowsum (max-free: |E*scale|<~8).
// GEMM schedule: per phase {ds_read issue; [stage]; barrier; MFMA under
// setprio (compiler lgkm waits)}; TRIPLE-buffered LDS (144 KiB) with
// counted vmcnt(6) -- never 0 mid-loop; XCD-bijective block swizzle;
// global_load_lds w=16; XOR-swizzled LDS (0 bank conflicts measured).
// R7 post-mortem: cross-kernel atomicAdd rowsum was the only replay-unproven
// mechanism and post-timing diverged -> replaced by PART writes + reduce.

typedef __attribute__((ext_vector_type(8))) short bf16x8;
typedef __attribute__((ext_vector_type(4))) float f32x4;
typedef __attribute__((ext_vector_type(8))) unsigned short u16x8;

#define DEVI static __device__ __forceinline__

DEVI unsigned short f2b(float x) {
  __hip_bfloat16 h = __float2bfloat16(x);
  return __builtin_bit_cast(unsigned short, h);
}

typedef const void __attribute__((address_space(1)))* gptr_t;
typedef void __attribute__((address_space(3)))* lptr_t;

DEVI void gload_lds16(const void* g, void* l) {
  __builtin_amdgcn_global_load_lds((gptr_t)g, (lptr_t)l, 16, 0, 0);
}

// ------------- f32 -> bf16 convert, z selects (k,v,q) -> contiguous dst ---
__global__ void cvt3_f32_to_bf16(const float* __restrict__ s0,
                                 const float* __restrict__ s1,
                                 const float* __restrict__ s2,
                                 u16x8* __restrict__ dst, int n8) {
  int i = blockIdx.x * 256 + threadIdx.x;
  if (i >= n8) return;
  const float* src = blockIdx.z == 0 ? s0 : (blockIdx.z == 1 ? s1 : s2);
  const float4* s4 = (const float4*)src;
  float4 a = s4[2 * i], b = s4[2 * i + 1];
  u16x8 o;
  o[0] = f2b(a.x); o[1] = f2b(a.y); o[2] = f2b(a.z); o[3] = f2b(a.w);
  o[4] = f2b(b.x); o[5] = f2b(b.y); o[6] = f2b(b.z); o[7] = f2b(b.w);
  dst[(long)blockIdx.z * n8 + i] = o;
}

// ---- W [512,512] f32 -> WT [512,512] bf16 transpose, z selects W ---------
__global__ void wtrans4_f32(const float* __restrict__ w0,
                            const float* __restrict__ w1,
                            const float* __restrict__ w2,
                            const float* __restrict__ w3,
                            unsigned short* __restrict__ WT) {
  __shared__ unsigned short s[32][33];
  const float* W = blockIdx.z == 0 ? w0 : (blockIdx.z == 1 ? w1
                   : (blockIdx.z == 2 ? w2 : w3));
  unsigned short* dst = WT + (long)blockIdx.z * 512 * 512;
  int tx = threadIdx.x, ty = threadIdx.y;   // (32,8)
  int bx = blockIdx.x, by = blockIdx.y;
#pragma unroll
  for (int i = 0; i < 32; i += 8)
    s[ty + i][tx] = f2b(W[(by * 32 + ty + i) * 512 + bx * 32 + tx]);
  __syncthreads();
#pragma unroll
  for (int i = 0; i < 32; i += 8)
    dst[(bx * 32 + ty + i) * 512 + by * 32 + tx] = s[tx][ty + i];
}

// ---- ROWSUM[r] = sum over 128 slots of PART[slot][r], r < 16384 ----------
__global__ __launch_bounds__(256) void reduce_partials(
    const float* __restrict__ part, float* __restrict__ rowsum) {
  int r = blockIdx.x * 256 + threadIdx.x;   // 16384 threads, coalesced
  float s = 0.f;
#pragma unroll 8
  for (int i = 0; i < 128; ++i) s += part[(long)i * 16384 + r];
  rowsum[r] = s;
}

// ------------- pipelined NT GEMM: C[M,N] = A[M,K]*B[N,K]^T ----------------
// EPI: 0 = bf16 store (+bz-selected bias if HAS_BIAS)
//      1 = P' = exp(acc*scale) bf16 store + PART[slot][row] partial sums
//      2 = f32 store, acc/rowsum[row] + bias0[col]
template <int BN, int EPI, bool HAS_BIAS>
__global__ __launch_bounds__(512, 2) void gemm8p(
    const unsigned short* __restrict__ A,
    const unsigned short* __restrict__ B,
    void* __restrict__ Cv,
    const float* __restrict__ bias0,
    const float* __restrict__ bias1,
    const float* __restrict__ bias2,
    float* __restrict__ rspart,   // EPI=1: PART base; EPI=2: ROWSUM base
    int M, int N, int K, long sA, long sB, long sC) {
  constexpr int WN = BN / 4;             // wave col-tile: 64 or 32
  constexpr int NFRAG = WN / 16;         // 4 or 2
  constexpr int MHALF = (BN == 256) ? 2 : 1;
  constexpr int MPP = 8 / MHALF;         // m-frags per phase: 4 or 8
  constexpr int BLOADS = BN / 64;        // stage loads for B: 4 or 2
  constexpr int NBUF = (BN == 128) ? 3 : 2;

  __shared__ unsigned short As[NBUF][256 * 64];
  __shared__ unsigned short Bs[NBUF][BN * 64];

  // XCD-bijective swizzle (nwg % 8 == 0 for every launch here).
  const int gx = gridDim.x, gy = gridDim.y;
  const int nwg = gx * gy * gridDim.z;
  const int orig = (blockIdx.z * gy + blockIdx.y) * gx + blockIdx.x;
  const int qch = nwg >> 3;
  const int wg = (orig & 7) * qch + (orig >> 3);
  const int bx = wg % gx;
  const int tmp = wg / gx;
  const int by = tmp % gy;
  const int bz = tmp / gy;

  const unsigned short* Ab = A + (long)bz * sA;
  const unsigned short* Bb = B + (long)bz * sB;

  const int t = threadIdx.x;
  const int lane = t & 63;
  const int wid = t >> 6;                // 8 waves: 2 (M) x 4 (N)
  const int wrow = wid >> 2, wcol = wid & 3;
  const int lr = lane & 15, lk = lane >> 4;
  const long row0 = (long)by * 256;
  const long col0 = (long)bx * BN;

  f32x4 acc[8][NFRAG] = {};

  auto stage = [&](int buf, int k0) {
#pragma unroll
    for (int p = 0; p < 4; ++p) {        // A: 256x64 bf16 = 32 KiB
      int gg = p * 512 + t;
      int r = gg >> 3, c = gg & 7;
      gload_lds16(Ab + (row0 + r) * (long)K + k0 + (c ^ (r & 7)) * 8,
                  (char*)As[buf] + gg * 16);
    }
#pragma unroll
    for (int p = 0; p < BLOADS; ++p) {   // B: BNx64
      int gg = p * 512 + t;
      int r = gg >> 3, c = gg & 7;
      gload_lds16(Bb + (col0 + r) * (long)K + k0 + (c ^ (r & 7)) * 8,
                  (char*)Bs[buf] + gg * 16);
    }
  };

  const int nt = K >> 6;
  // Prologue: fill NBUF-1 buffers; wait only for buffer 0.
  stage(0, 0);
  if constexpr (NBUF == 3) {
    stage(1, 64);
    asm volatile("s_waitcnt vmcnt(6)" ::: "memory");
  } else {
    asm volatile("s_waitcnt vmcnt(0)" ::: "memory");
  }
  __builtin_amdgcn_s_barrier();

  int cur = 0, stg = NBUF - 1;
  for (int tt = 0; tt < nt; ++tt) {
    const bool do_stage = (tt + NBUF - 1) < nt;
#pragma unroll
    for (int s = 0; s < 2; ++s) {
      bf16x8 bfr[NFRAG];
#pragma unroll
      for (int h = 0; h < MHALF; ++h) {
        bf16x8 af[MPP];
#pragma unroll
        for (int m = 0; m < MPP; ++m) {
          int rowA = wrow * 128 + (h * MPP + m) * 16 + lr;
          af[m] = *(const bf16x8*)((const char*)As[cur] + rowA * 128 +
                                   ((s * 4 + lk) ^ (rowA & 7)) * 16);
        }
        if (h == 0) {
#pragma unroll
          for (int n = 0; n < NFRAG; ++n) {
            int rowB = wcol * WN + n * 16 + lr;
            bfr[n] = *(const bf16x8*)((const char*)Bs[cur] + rowB * 128 +
                                      ((s * 4 + lk) ^ (rowB & 7)) * 16);
          }
        }
        // Stage tile tt+NBUF-1 into buffer `stg`: its last reads were in
        // tile tt-1, retired before that tile's closing barrier -> safe.
        if (s == 0 && h == 0 && do_stage) stage(stg, (tt + NBUF - 1) << 6);
        __builtin_amdgcn_sched_barrier(0);
        __builtin_amdgcn_s_barrier();
        // (compiler inserts fine-grained lgkmcnt before each MFMA use)
        __builtin_amdgcn_s_setprio(1);
#pragma unroll
        for (int m = 0; m < MPP; ++m)
#pragma unroll
          for (int n = 0; n < NFRAG; ++n)
            acc[h * MPP + m][n] = __builtin_amdgcn_mfma_f32_16x16x32_bf16(
                af[m], bfr[n], acc[h * MPP + m][n], 0, 0, 0);
        __builtin_amdgcn_s_setprio(0);
        if (s == 1 && h == MHALF - 1) {
          // Tile end: next tile's loads must be LDS-visible to ALL waves
          // after the closing barrier -> per-wave wait BEFORE the barrier.
          if constexpr (NBUF == 3) {
            if (do_stage)
              asm volatile("s_waitcnt vmcnt(6)" ::: "memory");  // counted
            else
              asm volatile("s_waitcnt vmcnt(0)" ::: "memory");  // tail drain
          } else {
            asm volatile("s_waitcnt vmcnt(0)" ::: "memory");
          }
          __builtin_amdgcn_sched_barrier(0);
        }
        __builtin_amdgcn_s_barrier();
      }
    }
    cur = (cur + 1 == NBUF) ? 0 : cur + 1;
    stg = (stg + 1 == NBUF) ? 0 : stg + 1;
  }
  __builtin_amdgcn_sched_barrier(0);

  const float kScale = 0.04419417382415922f;  // 1/sqrt(512)

  if constexpr (EPI == 1) {
    // P' = exp(acc*scale) -> bf16; per-(block_x, wave) partial row sums to
    // PART[slot][bz*M + row], slot = bx*4 + wcol in [0,128). Each (row,
    // slot) written exactly once -> deterministic, no atomics.
    const int slot = bx * 4 + wcol;
#pragma unroll
    for (int m = 0; m < 8; ++m) {
#pragma unroll
      for (int r = 0; r < 4; ++r) {
        long row = row0 + wrow * 128 + m * 16 + lk * 4 + r;
        float s = 0.f;
#pragma unroll
        for (int n = 0; n < NFRAG; ++n) {
          long col = col0 + wcol * WN + n * 16 + lr;
          float e = __expf(acc[m][n][r] * kScale);
          ((unsigned short*)Cv + bz * sC)[row * N + col] = f2b(e);
          s += e;
        }
        s += __shfl_xor(s, 1); s += __shfl_xor(s, 2);
        s += __shfl_xor(s, 4); s += __shfl_xor(s, 8);
        if ((lane & 15) == 0)
          rspart[(long)slot * 16384 + (long)bz * M + row] = s;
      }
    }
  } else if constexpr (EPI == 2) {
#pragma unroll
    for (int m = 0; m < 8; ++m) {
#pragma unroll
      for (int r = 0; r < 4; ++r) {
        long row = row0 + wrow * 128 + m * 16 + lk * 4 + r;
        float inv = 1.0f / rspart[(long)bz * M + row];
#pragma unroll
        for (int n = 0; n < NFRAG; ++n) {
          long col = col0 + wcol * WN + n * 16 + lr;
          float v = acc[m][n][r] * inv;
          if (HAS_BIAS) v += bias0[col];
          ((float*)Cv + bz * sC)[row * N + col] = v;
        }
      }
    }
  } else {
    const float* bias = bz == 0 ? bias0 : (bz == 1 ? bias1 : bias2);
#pragma unroll
    for (int m = 0; m < 8; ++m) {
#pragma unroll
      for (int n = 0; n < NFRAG; ++n) {
#pragma unroll
        for (int r = 0; r < 4; ++r) {
          long row = row0 + wrow * 128 + m * 16 + lk * 4 + r;
          long col = col0 + wcol * WN + n * 16 + lr;
          float v = acc[m][n][r];
          if (HAS_BIAS) v += bias[col];
          ((unsigned short*)Cv + bz * sC)[row * N + col] = f2b(v);
        }
      }
    }
  }
}

extern "C" void kernel_launch(void* const* d_in, const int* in_sizes, int n_in,
                              void* d_out, int out_size, void* d_ws, size_t ws_size,
                              hipStream_t stream) {
  const float* k_in = (const float*)d_in[0];
  const float* v_in = (const float*)d_in[1];
  const float* q_in = (const float*)d_in[2];
  const float* Wk = (const float*)d_in[3];
  const float* bk = (const float*)d_in[4];
  const float* Wv = (const float*)d_in[5];
  const float* bv = (const float*)d_in[6];
  const float* Wq = (const float*)d_in[7];
  const float* bq = (const float*)d_in[8];
  const float* Wo = (const float*)d_in[9];
  const float* bo = (const float*)d_in[10];

  const int B = 4, S = 4096, D = 512;
  const long BS = (long)B * S;      // 16384
  const size_t MB = 1024 * 1024;
  if (ws_size < 226 * MB) return;   // leaves d_out poisoned -> visible failure

  // Workspace (226 MiB):
  //   0..128   P0..P3 (P' = exp(E*scale), bf16; early: XK/XV/XQ 0..48)
  //   128..176 KP, VP, QP (16 MiB each, uniform stride)
  //   176..192 VWT ([512,4096] bf16 per batch)
  //   192..200 PART (128 x 16384 f32 partial row sums)
  //   200..201 ROWSUM (16384 f32)
  //   224..226 WTK,WTV,WTQ,WTO
  char* ws = (char*)d_ws;
  unsigned short* P    = (unsigned short*)(ws + 0);
  unsigned short* XK   = (unsigned short*)(ws + 0);
  unsigned short* KP   = (unsigned short*)(ws + 128 * MB);
  unsigned short* VP   = (unsigned short*)(ws + 144 * MB);
  unsigned short* QP   = (unsigned short*)(ws + 160 * MB);
  unsigned short* VWT  = (unsigned short*)(ws + 176 * MB);
  float* PART          = (float*)(ws + 192 * MB);
  float* ROWSUM        = (float*)(ws + 200 * MB);
  unsigned short* WTK  = (unsigned short*)(ws + 224 * MB);
  unsigned short* WTO  = WTK + 3L * 512 * 512;

  int n8 = (int)(BS * D / 8);
  cvt3_f32_to_bf16<<<dim3((n8 + 255) / 256, 1, 3), 256, 0, stream>>>(
      k_in, v_in, q_in, (u16x8*)XK, n8);

  wtrans4_f32<<<dim3(16, 16, 4), dim3(32, 8), 0, stream>>>(
      Wk, Wv, Wq, Wo, WTK);

  // K/V/Q projections, z=3: (X[z], WT[z]) -> {KP,VP,QP}[z], bias per z.
  gemm8p<128, 0, true><<<dim3(D / 128, BS / 256, 3), 512, 0, stream>>>(
      XK, WTK, KP, bk, bv, bq, nullptr, (int)BS, D, D,
      BS * D, (long)512 * 512, BS * D);

  // VWT[b] = (v_proj[b] @ Wo)^T == NT(A=WTO [512,512], B=VP[b] [4096,512]).
  gemm8p<128, 0, false><<<dim3(S / 128, D / 256, 4), 512, 0, stream>>>(
      WTO, VP, VWT, nullptr, nullptr, nullptr, nullptr, D, S, D,
      0, (long)S * D, (long)S * D);

  // P'[b] = exp(qp[b] @ kp[b]^T * scale) + PART partial sums, z=4.
  gemm8p<128, 1, false><<<dim3(S / 128, S / 256, 4), 512, 0, stream>>>(
      QP, KP, P, nullptr, nullptr, nullptr, PART, S, S, D,
      (long)S * D, (long)S * D, (long)S * S);

  // ROWSUM = sum over slots of PART.
  reduce_partials<<<64, 256, 0, stream>>>(PART, ROWSUM);

  // out[b] = (P'[b] @ VWT[b]^T)/rowsum + bo (f32 straight to d_out), z=4.
  gemm8p<128, 2, true><<<dim3(D / 128, S / 256, 4), 512, 0, stream>>>(
      P, VWT, d_out, bo, bo, bo, ROWSUM, S, D, S,
      (long)S * S, (long)S * D, (long)S * D);
}

// Round 9
// 270.792 us; speedup vs baseline: 1.1548x; 1.1548x over previous
//
#include <hip/hip_runtime.h>
#include <hip/hip_bf16.h>

// Self-attention: B=4, S=4096, D=512, f32 in/out, bf16 MFMA internally.
// cvt(q,k,v)->bf16 (z=3); W transpose->bf16 (z=4); proj GEMM (NT, z=3);
// VWT[b] = (v_proj @ Wo)^T via NT GEMM; E: P' = exp(qp@kp^T * scale) -> P
// region (z=4, BN=256 tile), per-(block,wave) partial row sums -> PART
// (deterministic, NO atomics); reduce_partials: ROWSUM = sum(PART);
// out = (P'@VWT^T)/rowsum + bo -> d_out (f32, z=4, BN=128).
// Softmax = exp/rowsum (max-free: |E*scale| <~ 8 for N(0,1)-scaled scores).
// GEMM schedule: per phase {ds_read issue; [stage]; barrier; MFMA under
// setprio (compiler lgkm waits)}; BN=128: TRIPLE-buffered LDS (144 KiB),
// counted vmcnt(6) never 0 mid-loop; BN=256: double-buffered 128 KiB
// (stage issued 4 phases before its tile-end wait -> wait is near-free).
// R8 post-mortem: E at BN=128 was 145us/474TF (L2 thrash, FETCH 136MB);
// BN=256 (R5) was 94.6us/726TF -> E reverted to the 256^2 tile.

typedef __attribute__((ext_vector_type(8))) short bf16x8;
typedef __attribute__((ext_vector_type(4))) float f32x4;
typedef __attribute__((ext_vector_type(8))) unsigned short u16x8;

#define DEVI static __device__ __forceinline__

DEVI unsigned short f2b(float x) {
  __hip_bfloat16 h = __float2bfloat16(x);
  return __builtin_bit_cast(unsigned short, h);
}

typedef const void __attribute__((address_space(1)))* gptr_t;
typedef void __attribute__((address_space(3)))* lptr_t;

DEVI void gload_lds16(const void* g, void* l) {
  __builtin_amdgcn_global_load_lds((gptr_t)g, (lptr_t)l, 16, 0, 0);
}

// ------------- f32 -> bf16 convert, z selects (k,v,q) -> contiguous dst ---
__global__ void cvt3_f32_to_bf16(const float* __restrict__ s0,
                                 const float* __restrict__ s1,
                                 const float* __restrict__ s2,
                                 u16x8* __restrict__ dst, int n8) {
  int i = blockIdx.x * 256 + threadIdx.x;
  if (i >= n8) return;
  const float* src = blockIdx.z == 0 ? s0 : (blockIdx.z == 1 ? s1 : s2);
  const float4* s4 = (const float4*)src;
  float4 a = s4[2 * i], b = s4[2 * i + 1];
  u16x8 o;
  o[0] = f2b(a.x); o[1] = f2b(a.y); o[2] = f2b(a.z); o[3] = f2b(a.w);
  o[4] = f2b(b.x); o[5] = f2b(b.y); o[6] = f2b(b.z); o[7] = f2b(b.w);
  dst[(long)blockIdx.z * n8 + i] = o;
}

// ---- W [512,512] f32 -> WT [512,512] bf16 transpose, z selects W ---------
__global__ void wtrans4_f32(const float* __restrict__ w0,
                            const float* __restrict__ w1,
                            const float* __restrict__ w2,
                            const float* __restrict__ w3,
                            unsigned short* __restrict__ WT) {
  __shared__ unsigned short s[32][33];
  const float* W = blockIdx.z == 0 ? w0 : (blockIdx.z == 1 ? w1
                   : (blockIdx.z == 2 ? w2 : w3));
  unsigned short* dst = WT + (long)blockIdx.z * 512 * 512;
  int tx = threadIdx.x, ty = threadIdx.y;   // (32,8)
  int bx = blockIdx.x, by = blockIdx.y;
#pragma unroll
  for (int i = 0; i < 32; i += 8)
    s[ty + i][tx] = f2b(W[(by * 32 + ty + i) * 512 + bx * 32 + tx]);
  __syncthreads();
#pragma unroll
  for (int i = 0; i < 32; i += 8)
    dst[(bx * 32 + ty + i) * 512 + by * 32 + tx] = s[tx][ty + i];
}

// ---- ROWSUM[r] = sum over NSLOT slots of PART[slot][r], r < 16384 --------
__global__ __launch_bounds__(256) void reduce_partials(
    const float* __restrict__ part, float* __restrict__ rowsum, int nslot) {
  int r = blockIdx.x * 256 + threadIdx.x;   // 16384 threads, coalesced
  float s = 0.f;
#pragma unroll 8
  for (int i = 0; i < nslot; ++i) s += part[(long)i * 16384 + r];
  rowsum[r] = s;
}

// ------------- pipelined NT GEMM: C[M,N] = A[M,K]*B[N,K]^T ----------------
// EPI: 0 = bf16 store (+bz-selected bias if HAS_BIAS)
//      1 = P' = exp(acc*scale) bf16 store + PART[slot][row] partial sums
//      2 = f32 store, acc/rowsum[row] + bias0[col]
template <int BN, int EPI, bool HAS_BIAS>
__global__ __launch_bounds__(512, 2) void gemm8p(
    const unsigned short* __restrict__ A,
    const unsigned short* __restrict__ B,
    void* __restrict__ Cv,
    const float* __restrict__ bias0,
    const float* __restrict__ bias1,
    const float* __restrict__ bias2,
    float* __restrict__ rspart,   // EPI=1: PART base; EPI=2: ROWSUM base
    int M, int N, int K, long sA, long sB, long sC) {
  constexpr int WN = BN / 4;             // wave col-tile: 64 or 32
  constexpr int NFRAG = WN / 16;         // 4 or 2
  constexpr int MHALF = (BN == 256) ? 2 : 1;
  constexpr int MPP = 8 / MHALF;         // m-frags per phase: 4 or 8
  constexpr int BLOADS = BN / 64;        // stage loads for B: 4 or 2
  constexpr int NBUF = (BN == 128) ? 3 : 2;

  __shared__ unsigned short As[NBUF][256 * 64];
  __shared__ unsigned short Bs[NBUF][BN * 64];

  // XCD-bijective swizzle (nwg % 8 == 0 for every launch here).
  const int gx = gridDim.x, gy = gridDim.y;
  const int nwg = gx * gy * gridDim.z;
  const int orig = (blockIdx.z * gy + blockIdx.y) * gx + blockIdx.x;
  const int qch = nwg >> 3;
  const int wg = (orig & 7) * qch + (orig >> 3);
  const int bx = wg % gx;
  const int tmp = wg / gx;
  const int by = tmp % gy;
  const int bz = tmp / gy;

  const unsigned short* Ab = A + (long)bz * sA;
  const unsigned short* Bb = B + (long)bz * sB;

  const int t = threadIdx.x;
  const int lane = t & 63;
  const int wid = t >> 6;                // 8 waves: 2 (M) x 4 (N)
  const int wrow = wid >> 2, wcol = wid & 3;
  const int lr = lane & 15, lk = lane >> 4;
  const long row0 = (long)by * 256;
  const long col0 = (long)bx * BN;

  f32x4 acc[8][NFRAG] = {};

  auto stage = [&](int buf, int k0) {
#pragma unroll
    for (int p = 0; p < 4; ++p) {        // A: 256x64 bf16 = 32 KiB
      int gg = p * 512 + t;
      int r = gg >> 3, c = gg & 7;
      gload_lds16(Ab + (row0 + r) * (long)K + k0 + (c ^ (r & 7)) * 8,
                  (char*)As[buf] + gg * 16);
    }
#pragma unroll
    for (int p = 0; p < BLOADS; ++p) {   // B: BNx64
      int gg = p * 512 + t;
      int r = gg >> 3, c = gg & 7;
      gload_lds16(Bb + (col0 + r) * (long)K + k0 + (c ^ (r & 7)) * 8,
                  (char*)Bs[buf] + gg * 16);
    }
  };

  const int nt = K >> 6;
  // Prologue: fill NBUF-1 buffers; wait only for buffer 0.
  stage(0, 0);
  if constexpr (NBUF == 3) {
    stage(1, 64);
    asm volatile("s_waitcnt vmcnt(6)" ::: "memory");
  } else {
    asm volatile("s_waitcnt vmcnt(0)" ::: "memory");
  }
  __builtin_amdgcn_s_barrier();

  int cur = 0, stg = NBUF - 1;
  for (int tt = 0; tt < nt; ++tt) {
    const bool do_stage = (tt + NBUF - 1) < nt;
#pragma unroll
    for (int s = 0; s < 2; ++s) {
      bf16x8 bfr[NFRAG];
#pragma unroll
      for (int h = 0; h < MHALF; ++h) {
        bf16x8 af[MPP];
#pragma unroll
        for (int m = 0; m < MPP; ++m) {
          int rowA = wrow * 128 + (h * MPP + m) * 16 + lr;
          af[m] = *(const bf16x8*)((const char*)As[cur] + rowA * 128 +
                                   ((s * 4 + lk) ^ (rowA & 7)) * 16);
        }
        if (h == 0) {
#pragma unroll
          for (int n = 0; n < NFRAG; ++n) {
            int rowB = wcol * WN + n * 16 + lr;
            bfr[n] = *(const bf16x8*)((const char*)Bs[cur] + rowB * 128 +
                                      ((s * 4 + lk) ^ (rowB & 7)) * 16);
          }
        }
        // Stage tile tt+NBUF-1 into buffer `stg`: its last reads were in
        // tile tt-1, retired before that tile's closing barrier -> safe.
        if (s == 0 && h == 0 && do_stage) stage(stg, (tt + NBUF - 1) << 6);
        __builtin_amdgcn_sched_barrier(0);
        __builtin_amdgcn_s_barrier();
        // (compiler inserts fine-grained lgkmcnt before each MFMA use)
        __builtin_amdgcn_s_setprio(1);
#pragma unroll
        for (int m = 0; m < MPP; ++m)
#pragma unroll
          for (int n = 0; n < NFRAG; ++n)
            acc[h * MPP + m][n] = __builtin_amdgcn_mfma_f32_16x16x32_bf16(
                af[m], bfr[n], acc[h * MPP + m][n], 0, 0, 0);
        __builtin_amdgcn_s_setprio(0);
        if (s == 1 && h == MHALF - 1) {
          // Tile end: next tile's loads must be LDS-visible to ALL waves
          // after the closing barrier -> per-wave wait BEFORE the barrier.
          if constexpr (NBUF == 3) {
            if (do_stage)
              asm volatile("s_waitcnt vmcnt(6)" ::: "memory");  // counted
            else
              asm volatile("s_waitcnt vmcnt(0)" ::: "memory");  // tail drain
          } else {
            // NBUF=2: loads issued 4 phases ago -> wait is near-free.
            asm volatile("s_waitcnt vmcnt(0)" ::: "memory");
          }
          __builtin_amdgcn_sched_barrier(0);
        }
        __builtin_amdgcn_s_barrier();
      }
    }
    cur = (cur + 1 == NBUF) ? 0 : cur + 1;
    stg = (stg + 1 == NBUF) ? 0 : stg + 1;
  }
  __builtin_amdgcn_sched_barrier(0);

  const float kScale = 0.04419417382415922f;  // 1/sqrt(512)

  if constexpr (EPI == 1) {
    // P' = exp(acc*scale) -> bf16; per-(block_x, wave) partial row sums to
    // PART[slot][bz*M + row], slot = bx*4 + wcol in [0, gx*4). Each (row,
    // slot) written exactly once -> deterministic, no atomics.
    const int slot = bx * 4 + wcol;
#pragma unroll
    for (int m = 0; m < 8; ++m) {
#pragma unroll
      for (int r = 0; r < 4; ++r) {
        long row = row0 + wrow * 128 + m * 16 + lk * 4 + r;
        float s = 0.f;
#pragma unroll
        for (int n = 0; n < NFRAG; ++n) {
          long col = col0 + wcol * WN + n * 16 + lr;
          float e = __expf(acc[m][n][r] * kScale);
          ((unsigned short*)Cv + bz * sC)[row * N + col] = f2b(e);
          s += e;
        }
        s += __shfl_xor(s, 1); s += __shfl_xor(s, 2);
        s += __shfl_xor(s, 4); s += __shfl_xor(s, 8);
        if ((lane & 15) == 0)
          rspart[(long)slot * 16384 + (long)bz * M + row] = s;
      }
    }
  } else if constexpr (EPI == 2) {
#pragma unroll
    for (int m = 0; m < 8; ++m) {
#pragma unroll
      for (int r = 0; r < 4; ++r) {
        long row = row0 + wrow * 128 + m * 16 + lk * 4 + r;
        float inv = 1.0f / rspart[(long)bz * M + row];
#pragma unroll
        for (int n = 0; n < NFRAG; ++n) {
          long col = col0 + wcol * WN + n * 16 + lr;
          float v = acc[m][n][r] * inv;
          if (HAS_BIAS) v += bias0[col];
          ((float*)Cv + bz * sC)[row * N + col] = v;
        }
      }
    }
  } else {
    const float* bias = bz == 0 ? bias0 : (bz == 1 ? bias1 : bias2);
#pragma unroll
    for (int m = 0; m < 8; ++m) {
#pragma unroll
      for (int n = 0; n < NFRAG; ++n) {
#pragma unroll
        for (int r = 0; r < 4; ++r) {
          long row = row0 + wrow * 128 + m * 16 + lk * 4 + r;
          long col = col0 + wcol * WN + n * 16 + lr;
          float v = acc[m][n][r];
          if (HAS_BIAS) v += bias[col];
          ((unsigned short*)Cv + bz * sC)[row * N + col] = f2b(v);
        }
      }
    }
  }
}

extern "C" void kernel_launch(void* const* d_in, const int* in_sizes, int n_in,
                              void* d_out, int out_size, void* d_ws, size_t ws_size,
                              hipStream_t stream) {
  const float* k_in = (const float*)d_in[0];
  const float* v_in = (const float*)d_in[1];
  const float* q_in = (const float*)d_in[2];
  const float* Wk = (const float*)d_in[3];
  const float* bk = (const float*)d_in[4];
  const float* Wv = (const float*)d_in[5];
  const float* bv = (const float*)d_in[6];
  const float* Wq = (const float*)d_in[7];
  const float* bq = (const float*)d_in[8];
  const float* Wo = (const float*)d_in[9];
  const float* bo = (const float*)d_in[10];

  const int B = 4, S = 4096, D = 512;
  const long BS = (long)B * S;      // 16384
  const size_t MB = 1024 * 1024;
  if (ws_size < 226 * MB) return;   // leaves d_out poisoned -> visible failure

  // Workspace (226 MiB):
  //   0..128   P0..P3 (P' = exp(E*scale), bf16; early: XK/XV/XQ 0..48)
  //   128..176 KP, VP, QP (16 MiB each, uniform stride)
  //   176..192 VWT ([512,4096] bf16 per batch)
  //   192..200 PART (<=128 x 16384 f32 partial row sums; 64 slots used)
  //   200..201 ROWSUM (16384 f32)
  //   224..226 WTK,WTV,WTQ,WTO
  char* ws = (char*)d_ws;
  unsigned short* P    = (unsigned short*)(ws + 0);
  unsigned short* XK   = (unsigned short*)(ws + 0);
  unsigned short* KP   = (unsigned short*)(ws + 128 * MB);
  unsigned short* VP   = (unsigned short*)(ws + 144 * MB);
  unsigned short* QP   = (unsigned short*)(ws + 160 * MB);
  unsigned short* VWT  = (unsigned short*)(ws + 176 * MB);
  float* PART          = (float*)(ws + 192 * MB);
  float* ROWSUM        = (float*)(ws + 200 * MB);
  unsigned short* WTK  = (unsigned short*)(ws + 224 * MB);
  unsigned short* WTO  = WTK + 3L * 512 * 512;

  int n8 = (int)(BS * D / 8);
  cvt3_f32_to_bf16<<<dim3((n8 + 255) / 256, 1, 3), 256, 0, stream>>>(
      k_in, v_in, q_in, (u16x8*)XK, n8);

  wtrans4_f32<<<dim3(16, 16, 4), dim3(32, 8), 0, stream>>>(
      Wk, Wv, Wq, Wo, WTK);

  // K/V/Q projections, z=3: (X[z], WT[z]) -> {KP,VP,QP}[z], bias per z.
  gemm8p<128, 0, true><<<dim3(D / 128, BS / 256, 3), 512, 0, stream>>>(
      XK, WTK, KP, bk, bv, bq, nullptr, (int)BS, D, D,
      BS * D, (long)512 * 512, BS * D);

  // VWT[b] = (v_proj[b] @ Wo)^T == NT(A=WTO [512,512], B=VP[b] [4096,512]).
  gemm8p<128, 0, false><<<dim3(S / 128, D / 256, 4), 512, 0, stream>>>(
      WTO, VP, VWT, nullptr, nullptr, nullptr, nullptr, D, S, D,
      0, (long)S * D, (long)S * D);

  // P'[b] = exp(qp[b] @ kp[b]^T * scale) + PART partial sums, z=4.
  // BN=256 tile (R5-proven shape for the square GEMM): 16x16x4 = 1024 wgs.
  gemm8p<256, 1, false><<<dim3(S / 256, S / 256, 4), 512, 0, stream>>>(
      QP, KP, P, nullptr, nullptr, nullptr, PART, S, S, D,
      (long)S * D, (long)S * D, (long)S * S);

  // ROWSUM = sum over 64 slots of PART.
  reduce_partials<<<64, 256, 0, stream>>>(PART, ROWSUM, (S / 256) * 4);

  // out[b] = (P'[b] @ VWT[b]^T)/rowsum + bo (f32 straight to d_out), z=4.
  gemm8p<128, 2, true><<<dim3(D / 128, S / 256, 4), 512, 0, stream>>>(
      P, VWT, d_out, bo, bo, bo, ROWSUM, S, D, S,
      (long)S * S, (long)S * D, (long)S * D);
}